// Round 8
// baseline (79.263 us; speedup 1.0000x reference)
//
#include <hip/hip_runtime.h>
#include <hip/hip_bf16.h>

// FirDownsample: y = depthwise FIR(4x4 separable [1,3,3,1]) on x (pad 2),
// out = conv3x3(y, w), stride 2.  x:(16,320,64,64) f32, out:(16,320,32,32) f32.
//
// R8: conv LDS re-mapped to s-major octet regions (4 x 297 16B-units) so
// global_load_lds staging is contiguous per instruction again (R7 regression fix),
// while keeping R7's octet-major y layout that makes fir's stores 16B-coalesced.
// LDS dbuf shrinks to 2 x 20,480B -> exactly 4 blocks/CU.
//   K1 fir_kernel : x -> y[n][qg=40][r][c][8ci] bf16
//   K2 wt2_kernel : w -> wt2[tap][cc][q][co][8ci] bf16
//   K3 conv_kernel: M64xN64 block, 4 waves M64xN16, B reg-dbuf, A via global_load_lds.

typedef short bf16x8_t __attribute__((ext_vector_type(8)));
typedef float f32x4 __attribute__((ext_vector_type(4)));
typedef unsigned int u32x4 __attribute__((ext_vector_type(4)));
typedef __attribute__((address_space(1))) const unsigned int* as1_u32p;
typedef __attribute__((address_space(3))) unsigned int* as3_u32p;

#define NI 16
#define CCH 320
#define HW 64
#define HY 65
#define HY2 4225           // 65*65
#define CCSTEP 135200      // 4*4225*8 shorts per cc (4 octets)

// ---------------- K1: separable FIR, x(f32) -> y bf16 [n][qg=40][r][c][8ci] ----------------
// block = (n, row-band of 8, 16-ci group). vert pass -> LDS [j][ci16][69] f32,
// horiz pass: thread owns (c, ci-octet) -> 16B stores, 64 lanes contiguous.
__global__ __launch_bounds__(256) void fir_kernel(const float* __restrict__ x,
                                                  const float* __restrict__ fir_k,
                                                  __hip_bfloat16* __restrict__ yt) {
    __shared__ float vlds[8 * 16 * 69];  // [j][ci16][cc69] : 35,328 B
    int bx = blockIdx.x;
    int n   = bx / 180;
    int rr  = bx % 180;
    int r0  = (rr / 20) * 8;
    int ci0 = (rr % 20) * 16;

    float f0 = fir_k[0] + fir_k[1] + fir_k[2] + fir_k[3];
    float f1 = fir_k[4] + fir_k[5] + fir_k[6] + fir_k[7];
    float f2 = fir_k[8] + fir_k[9] + fir_k[10] + fir_k[11];
    float f3 = fir_k[12] + fir_k[13] + fir_k[14] + fir_k[15];

    int tid = threadIdx.x;
    int lane = tid & 63;   // = w (vert), = c (horiz)
    int g = tid >> 6;      // wave id

    // vertical pass: vert[j][ci][w+2] = sum_a f[a] * x[r0+j-2+a][w]
    for (int cis = g; cis < 16; cis += 4) {
        int ci = ci0 + cis;
        const float* xb = x + (size_t)(n * CCH + ci) * HW * HW;
        float xr[11];
#pragma unroll
        for (int jr = 0; jr < 11; ++jr) {
            int row = r0 + jr - 2;
            xr[jr] = (row >= 0 && row < HW) ? xb[row * HW + lane] : 0.f;
        }
#pragma unroll
        for (int j = 0; j < 8; ++j) {
            float v = f0 * xr[j] + f1 * xr[j + 1] + f2 * xr[j + 2] + f3 * xr[j + 3];
            float* vrow = vlds + (j * 16 + cis) * 69;
            vrow[lane + 2] = v;                       // cc = w+2 (2..65)
            if (lane < 2)   vrow[lane] = 0.f;         // cc 0,1
            if (lane >= 62) vrow[lane + 4] = 0.f;     // cc 66,67
        }
    }
    __syncthreads();

    // horizontal pass: slot = (j, oct); wave-uniform slot, c = lane (+ lane63 does c=64)
    unsigned short* yu = (unsigned short*)yt;
#pragma unroll
    for (int i = 0; i < 4; ++i) {
        int slot = 4 * i + g;            // 0..15
        int j = slot >> 1, oct = slot & 1;
        int r = r0 + j;
        if (r >= HY) continue;
        int qg = (rr % 20) * 2 + oct;    // global ci-octet 0..39
        size_t obase = ((size_t)(n * 40 + qg) * HY2 + (size_t)r * HY) * 8;
        const float* vb = vlds + (j * 16 + oct * 8) * 69;
        int nc = (lane == 63) ? 2 : 1;
        for (int e = 0; e < nc; ++e) {
            int c = lane + e;            // 0..64
            float a[8];
#pragma unroll
            for (int u = 0; u < 8; ++u) {
                const float* vr = vb + u * 69 + c;
                a[u] = f0 * vr[0] + f1 * vr[1] + f2 * vr[2] + f3 * vr[3];
            }
            unsigned int wd[4];
#pragma unroll
            for (int h = 0; h < 4; ++h) {
                unsigned int lo = __bfloat16_as_ushort(__float2bfloat16(a[2 * h]));
                unsigned int hi = __bfloat16_as_ushort(__float2bfloat16(a[2 * h + 1]));
                wd[h] = lo | (hi << 16);
            }
            *(u32x4*)(yu + obase + (size_t)c * 8) = (u32x4){wd[0], wd[1], wd[2], wd[3]};
        }
    }
}

// ---------------- K2: w (co,ci,3,3) f32 -> wt2[tap][cc][q][co][8] bf16 ----------------
__global__ __launch_bounds__(256) void wt2_kernel(const float* __restrict__ w,
                                                  __hip_bfloat16* __restrict__ wt) {
    int idx = blockIdx.x * 256 + threadIdx.x;
    if (idx < 9 * CCH * CCH) {
        int j  = idx & 7;
        int co = (idx >> 3) % CCH;
        int t2 = idx / 2560;          // tap*40 + cc*4 + q
        int q  = t2 & 3;
        int cc = (t2 >> 2) % 10;
        int tap = t2 / 40;
        int ci = cc * 32 + q * 8 + j;
        wt[idx] = __float2bfloat16(w[(co * CCH + ci) * 9 + tap]);
    }
}

// ---------------- K3: MFMA conv, M64 x N64, waves M64xN16, B reg-dbuf ----------------
// grid = (n*5 + cb)*16 + sp ; wave wid owns co chunk wid*16.
// LDS per buffer: 4 octet-regions x 297 position-units (16B), padded to 1280 units.
// unit v = s*297 + p (p = pr*33 + pc). Staging: consecutive v -> consecutive global
// addresses within an octet region (contiguous bursts). A-read: unit = q*297 + p,
// 297 % 8 == 1 -> clusters (q + 2*lc) % 8 uniform -> conflict-free b128.
__global__ __launch_bounds__(256, 4) void conv_kernel(const __hip_bfloat16* __restrict__ yt,
                                                      const __hip_bfloat16* __restrict__ wt2,
                                                      float* __restrict__ out) {
    __shared__ short ylds[2][1280 * 8];   // 2 x 20,480 B

    int bx = blockIdx.x;
    int sp = bx & 15;
    int t  = bx >> 4;
    int cb = t % 5;
    int n  = t / 5;
    int co0 = cb * 64;
    int oh0 = (sp >> 1) * 4;
    int ow0 = (sp & 1) * 16;

    int tid = threadIdx.x;
    int lane = tid & 63;
    int wid = tid >> 6;
    int q = lane >> 4, lc = lane & 15;

    const unsigned short* ytu = (const unsigned short*)yt;
    const unsigned short* wtu = (const unsigned short*)wt2;

    // per-lane global source offsets (shorts) for staging units, cc=0.
    // y layout [n][cc*4+s][r][c][8]: off = ((n*40 + cc*4 + s)*HY2 + r*HY + c)*8
    int ybase = n * 40 * HY2 * 8 + ((2 * oh0) * HY + 2 * ow0) * 8;
    int goff[5];
#pragma unroll
    for (int k = 0; k < 5; ++k) {
        int u = k * 256 + tid;
        int uc = (u < 1188) ? u : 1187;    // tail: safe dup, lands in pad units
        int s = uc / 297, p = uc % 297;
        int pr = p / 33, pc = p - pr * 33;
        goff[k] = ybase + (s * HY2 + pr * HY + pc) * 8;
    }

    const unsigned short* wbl = wtu + q * 2560 + (size_t)(co0 + wid * 16 + lc) * 8;
    const int aoff = (q * 297 + 2 * lc) * 8;   // short-index within buffer

    f32x4 acc[4];
#pragma unroll
    for (int i = 0; i < 4; ++i) acc[i] = (f32x4){0.f, 0.f, 0.f, 0.f};

    bf16x8_t bfr[2][9];

    // wave-uniform LDS unit base for stage issue k: (k*256 + wid*64) units
#define GLDS(buf, K, ccidx)                                                            \
    __builtin_amdgcn_global_load_lds(                                                  \
        (as1_u32p)(ytu + goff[K] + (ccidx) * CCSTEP),                                  \
        (as3_u32p)(&ylds[buf][(size_t)((K) * 256 + wid * 64) * 8]), 16, 0, 0)

    // prologue: stage A(0) -> buf0, load B(0) -> bfr[0]
#pragma unroll
    for (int k = 0; k < 5; ++k) GLDS(0, k, 0);
#pragma unroll
    for (int kk = 0; kk < 9; ++kk)
        bfr[0][kk] = *(const bf16x8_t*)(wbl + kk * 102400);
    __syncthreads();

    auto compute = [&](const short* buf, const bf16x8_t* b) {
#pragma unroll
        for (int kw = 0; kw < 3; ++kw) {
            bf16x8_t af[9];
#pragma unroll
            for (int r = 0; r < 9; ++r)
                af[r] = *(const bf16x8_t*)(buf + aoff + (r * 33 + kw) * 8);
#pragma unroll
            for (int kh = 0; kh < 3; ++kh)
#pragma unroll
                for (int mf = 0; mf < 4; ++mf)
                    acc[mf] = __builtin_amdgcn_mfma_f32_16x16x32_bf16(
                        b[kh * 3 + kw], af[2 * mf + kh], acc[mf], 0, 0, 0);
        }
    };

    for (int tt = 0; tt < 5; ++tt) {
        int cc0 = 2 * tt, cc1 = 2 * tt + 1;
        // ---- even cc: compute from buf0/bfr[0]; prefetch cc0+1 -> buf1/bfr[1]
        {
#pragma unroll
            for (int k = 0; k < 5; ++k) GLDS(1, k, cc0 + 1);
            const unsigned short* wnx = wbl + (cc0 + 1) * 10240;
#pragma unroll
            for (int kk = 0; kk < 9; ++kk)
                bfr[1][kk] = *(const bf16x8_t*)(wnx + kk * 102400);
            compute(&ylds[0][0], bfr[0]);
            __syncthreads();   // drains vmcnt -> A(cc0+1) in LDS, bfr[1] ready
        }
        // ---- odd cc: compute from buf1/bfr[1]; prefetch cc1+1 -> buf0/bfr[0]
        {
            if (cc1 < 9) {
#pragma unroll
                for (int k = 0; k < 5; ++k) GLDS(0, k, cc1 + 1);
                const unsigned short* wnx = wbl + (cc1 + 1) * 10240;
#pragma unroll
                for (int kk = 0; kk < 9; ++kk)
                    bfr[0][kk] = *(const bf16x8_t*)(wnx + kk * 102400);
            }
            compute(&ylds[1][0], bfr[1]);
            if (cc1 < 9) __syncthreads();
        }
    }
#undef GLDS

    // epilogue: D[row=co][col=m]; coalesced 64B segments
#pragma unroll
    for (int mf = 0; mf < 4; ++mf) {
        int oh = oh0 + mf;
        int ow = ow0 + lc;
#pragma unroll
        for (int rg = 0; rg < 4; ++rg) {
            int co = co0 + wid * 16 + q * 4 + rg;
            out[((n * CCH + co) * 32 + oh) * 32 + ow] = acc[mf][rg];
        }
    }
}

// ---------------- Fallback: naive direct (correct, slow) ----------------
__global__ __launch_bounds__(256) void naive_kernel(const float* __restrict__ x,
                                                    const float* __restrict__ w,
                                                    const float* __restrict__ fk,
                                                    float* __restrict__ out) {
    int idx = blockIdx.x * 256 + threadIdx.x;
    if (idx >= NI * CCH * 32 * 32) return;
    int ow = idx & 31;
    int oh = (idx >> 5) & 31;
    int co = (idx >> 10) % CCH;
    int n = (idx >> 10) / CCH;
    float f0 = fk[0] + fk[1] + fk[2] + fk[3];
    float f1 = fk[4] + fk[5] + fk[6] + fk[7];
    float f2 = fk[8] + fk[9] + fk[10] + fk[11];
    float f3 = fk[12] + fk[13] + fk[14] + fk[15];
    float fv[4] = {f0, f1, f2, f3};
    float acc = 0.f;
    for (int ci = 0; ci < CCH; ++ci) {
        const float* xb = x + (size_t)(n * CCH + ci) * HW * HW;
        const float* wb = w + (size_t)(co * CCH + ci) * 9;
#pragma unroll
        for (int u = 0; u < 3; ++u) {
            int yr = 2 * oh + u;
#pragma unroll
            for (int v = 0; v < 3; ++v) {
                int yc = 2 * ow + v;
                float s = 0.f;
#pragma unroll
                for (int a = 0; a < 4; ++a) {
                    int xrw = yr - 2 + a;
                    if (xrw < 0 || xrw >= HW) continue;
                    float t = 0.f;
#pragma unroll
                    for (int b = 0; b < 4; ++b) {
                        int xc = yc - 2 + b;
                        if (xc >= 0 && xc < HW) t += fv[b] * xb[xrw * HW + xc];
                    }
                    s += fv[a] * t;
                }
                acc += wb[u * 3 + v] * s;
            }
        }
    }
    out[idx] = acc;
}

extern "C" void kernel_launch(void* const* d_in, const int* in_sizes, int n_in,
                              void* d_out, int out_size, void* d_ws, size_t ws_size,
                              hipStream_t stream) {
    const float* x = (const float*)d_in[0];
    const float* w = (const float*)d_in[1];
    const float* fk = (const float*)d_in[2];
    float* out = (float*)d_out;

    const size_t ybytes = (size_t)NI * 40 * HY2 * 8 * 2;      // 43,264,000
    const size_t wtoff = ybytes;
    const size_t need = wtoff + (size_t)9 * CCH * CCH * 2;    // 45,107,200

    if (ws_size >= need) {
        __hip_bfloat16* yt = (__hip_bfloat16*)d_ws;
        __hip_bfloat16* wt = (__hip_bfloat16*)((char*)d_ws + wtoff);
        fir_kernel<<<16 * 9 * 20, 256, 0, stream>>>(x, fk, yt);
        wt2_kernel<<<(9 * CCH * CCH + 255) / 256, 256, 0, stream>>>(w, wt);
        conv_kernel<<<16 * 5 * 16, 256, 0, stream>>>(yt, wt, out);
    } else {
        naive_kernel<<<(NI * CCH * 32 * 32 + 255) / 256, 256, 0, stream>>>(x, w, fk, out);
    }
}

// Round 9
// 79.005 us; speedup vs baseline: 1.0033x; 1.0033x over previous
//
#include <hip/hip_runtime.h>
#include <hip/hip_bf16.h>

// FirDownsample: y = depthwise FIR(4x4 separable [1,3,3,1]) on x (pad 2),
// out = conv3x3(y, w), stride 2.  x:(16,320,64,64) f32, out:(16,320,32,32) f32.
//
// R9 = R8 + XCD-aware bijective block swizzle in conv (T1): 1280 blocks = 8 XCD
// x 160; each XCD owns 2 complete n (y[n] = 2.7MB fits its 4MB L2), and the 5
// cb-blocks sharing a y-window are consecutive wgids. y re-reads move L3 -> L2.
//   K1 fir_kernel : x -> y[n][qg=40][r][c][8ci] bf16
//   K2 wt2_kernel : w -> wt2[tap][cc][q][co][8ci] bf16
//   K3 conv_kernel: M64xN64 block, 4 waves M64xN16, B reg-dbuf, A via global_load_lds.

typedef short bf16x8_t __attribute__((ext_vector_type(8)));
typedef float f32x4 __attribute__((ext_vector_type(4)));
typedef unsigned int u32x4 __attribute__((ext_vector_type(4)));
typedef __attribute__((address_space(1))) const unsigned int* as1_u32p;
typedef __attribute__((address_space(3))) unsigned int* as3_u32p;

#define NI 16
#define CCH 320
#define HW 64
#define HY 65
#define HY2 4225           // 65*65
#define CCSTEP 135200      // 4*4225*8 shorts per cc (4 octets)

// ---------------- K1: separable FIR, x(f32) -> y bf16 [n][qg=40][r][c][8ci] ----------------
__global__ __launch_bounds__(256) void fir_kernel(const float* __restrict__ x,
                                                  const float* __restrict__ fir_k,
                                                  __hip_bfloat16* __restrict__ yt) {
    __shared__ float vlds[8 * 16 * 69];  // [j][ci16][cc69] : 35,328 B
    int bx = blockIdx.x;
    int n   = bx / 180;
    int rr  = bx % 180;
    int r0  = (rr / 20) * 8;
    int ci0 = (rr % 20) * 16;

    float f0 = fir_k[0] + fir_k[1] + fir_k[2] + fir_k[3];
    float f1 = fir_k[4] + fir_k[5] + fir_k[6] + fir_k[7];
    float f2 = fir_k[8] + fir_k[9] + fir_k[10] + fir_k[11];
    float f3 = fir_k[12] + fir_k[13] + fir_k[14] + fir_k[15];

    int tid = threadIdx.x;
    int lane = tid & 63;   // = w (vert), = c (horiz)
    int g = tid >> 6;      // wave id

    // vertical pass: vert[j][ci][w+2] = sum_a f[a] * x[r0+j-2+a][w]
    for (int cis = g; cis < 16; cis += 4) {
        int ci = ci0 + cis;
        const float* xb = x + (size_t)(n * CCH + ci) * HW * HW;
        float xr[11];
#pragma unroll
        for (int jr = 0; jr < 11; ++jr) {
            int row = r0 + jr - 2;
            xr[jr] = (row >= 0 && row < HW) ? xb[row * HW + lane] : 0.f;
        }
#pragma unroll
        for (int j = 0; j < 8; ++j) {
            float v = f0 * xr[j] + f1 * xr[j + 1] + f2 * xr[j + 2] + f3 * xr[j + 3];
            float* vrow = vlds + (j * 16 + cis) * 69;
            vrow[lane + 2] = v;                       // cc = w+2 (2..65)
            if (lane < 2)   vrow[lane] = 0.f;         // cc 0,1
            if (lane >= 62) vrow[lane + 4] = 0.f;     // cc 66,67
        }
    }
    __syncthreads();

    // horizontal pass: slot = (j, oct); wave-uniform slot, c = lane (+ lane63 does c=64)
    unsigned short* yu = (unsigned short*)yt;
#pragma unroll
    for (int i = 0; i < 4; ++i) {
        int slot = 4 * i + g;            // 0..15
        int j = slot >> 1, oct = slot & 1;
        int r = r0 + j;
        if (r >= HY) continue;
        int qg = (rr % 20) * 2 + oct;    // global ci-octet 0..39
        size_t obase = ((size_t)(n * 40 + qg) * HY2 + (size_t)r * HY) * 8;
        const float* vb = vlds + (j * 16 + oct * 8) * 69;
        int nc = (lane == 63) ? 2 : 1;
        for (int e = 0; e < nc; ++e) {
            int c = lane + e;            // 0..64
            float a[8];
#pragma unroll
            for (int u = 0; u < 8; ++u) {
                const float* vr = vb + u * 69 + c;
                a[u] = f0 * vr[0] + f1 * vr[1] + f2 * vr[2] + f3 * vr[3];
            }
            unsigned int wd[4];
#pragma unroll
            for (int h = 0; h < 4; ++h) {
                unsigned int lo = __bfloat16_as_ushort(__float2bfloat16(a[2 * h]));
                unsigned int hi = __bfloat16_as_ushort(__float2bfloat16(a[2 * h + 1]));
                wd[h] = lo | (hi << 16);
            }
            *(u32x4*)(yu + obase + (size_t)c * 8) = (u32x4){wd[0], wd[1], wd[2], wd[3]};
        }
    }
}

// ---------------- K2: w (co,ci,3,3) f32 -> wt2[tap][cc][q][co][8] bf16 ----------------
__global__ __launch_bounds__(256) void wt2_kernel(const float* __restrict__ w,
                                                  __hip_bfloat16* __restrict__ wt) {
    int idx = blockIdx.x * 256 + threadIdx.x;
    if (idx < 9 * CCH * CCH) {
        int j  = idx & 7;
        int co = (idx >> 3) % CCH;
        int t2 = idx / 2560;          // tap*40 + cc*4 + q
        int q  = t2 & 3;
        int cc = (t2 >> 2) % 10;
        int tap = t2 / 40;
        int ci = cc * 32 + q * 8 + j;
        wt[idx] = __float2bfloat16(w[(co * CCH + ci) * 9 + tap]);
    }
}

// ---------------- K3: MFMA conv, M64 x N64, waves M64xN16, B reg-dbuf ----------------
// XCD swizzle: wg = (bx%8)*160 + bx/8  (bijective, 1280 = 8*160). Each XCD owns
// n in {2x, 2x+1}; within XCD: wg%80 = sp*5 + cb -> the 5 cb-copies of a y-window
// are consecutive. LDS per buffer: 4 octet-regions x 297 16B-units (pad to 1280).
// Staging contiguous per wave; A-read unit = q*297 + p, conflict-free b128.
__global__ __launch_bounds__(256, 4) void conv_kernel(const __hip_bfloat16* __restrict__ yt,
                                                      const __hip_bfloat16* __restrict__ wt2,
                                                      float* __restrict__ out) {
    __shared__ short ylds[2][1280 * 8];   // 2 x 20,480 B

    int bx = blockIdx.x;
    int wg = (bx & 7) * 160 + (bx >> 3);   // XCD-chunked bijective remap
    int n  = wg / 80;
    int r2 = wg % 80;
    int sp = r2 / 5;
    int cb = r2 % 5;
    int co0 = cb * 64;
    int oh0 = (sp >> 1) * 4;
    int ow0 = (sp & 1) * 16;

    int tid = threadIdx.x;
    int lane = tid & 63;
    int wid = tid >> 6;
    int q = lane >> 4, lc = lane & 15;

    const unsigned short* ytu = (const unsigned short*)yt;
    const unsigned short* wtu = (const unsigned short*)wt2;

    // per-lane global source offsets (shorts) for staging units, cc=0.
    // y layout [n][cc*4+s][r][c][8]: off = ((n*40 + cc*4 + s)*HY2 + r*HY + c)*8
    int ybase = n * 40 * HY2 * 8 + ((2 * oh0) * HY + 2 * ow0) * 8;
    int goff[5];
#pragma unroll
    for (int k = 0; k < 5; ++k) {
        int u = k * 256 + tid;
        int uc = (u < 1188) ? u : 1187;    // tail: safe dup, lands in pad units
        int s = uc / 297, p = uc % 297;
        int pr = p / 33, pc = p - pr * 33;
        goff[k] = ybase + (s * HY2 + pr * HY + pc) * 8;
    }

    const unsigned short* wbl = wtu + q * 2560 + (size_t)(co0 + wid * 16 + lc) * 8;
    const int aoff = (q * 297 + 2 * lc) * 8;   // short-index within buffer

    f32x4 acc[4];
#pragma unroll
    for (int i = 0; i < 4; ++i) acc[i] = (f32x4){0.f, 0.f, 0.f, 0.f};

    bf16x8_t bfr[2][9];

    // wave-uniform LDS unit base for stage issue k: (k*256 + wid*64) units
#define GLDS(buf, K, ccidx)                                                            \
    __builtin_amdgcn_global_load_lds(                                                  \
        (as1_u32p)(ytu + goff[K] + (ccidx) * CCSTEP),                                  \
        (as3_u32p)(&ylds[buf][(size_t)((K) * 256 + wid * 64) * 8]), 16, 0, 0)

    // prologue: stage A(0) -> buf0, load B(0) -> bfr[0]
#pragma unroll
    for (int k = 0; k < 5; ++k) GLDS(0, k, 0);
#pragma unroll
    for (int kk = 0; kk < 9; ++kk)
        bfr[0][kk] = *(const bf16x8_t*)(wbl + kk * 102400);
    __syncthreads();

    auto compute = [&](const short* buf, const bf16x8_t* b) {
#pragma unroll
        for (int kw = 0; kw < 3; ++kw) {
            bf16x8_t af[9];
#pragma unroll
            for (int r = 0; r < 9; ++r)
                af[r] = *(const bf16x8_t*)(buf + aoff + (r * 33 + kw) * 8);
#pragma unroll
            for (int kh = 0; kh < 3; ++kh)
#pragma unroll
                for (int mf = 0; mf < 4; ++mf)
                    acc[mf] = __builtin_amdgcn_mfma_f32_16x16x32_bf16(
                        b[kh * 3 + kw], af[2 * mf + kh], acc[mf], 0, 0, 0);
        }
    };

    for (int tt = 0; tt < 5; ++tt) {
        int cc0 = 2 * tt, cc1 = 2 * tt + 1;
        // ---- even cc: compute from buf0/bfr[0]; prefetch cc0+1 -> buf1/bfr[1]
        {
#pragma unroll
            for (int k = 0; k < 5; ++k) GLDS(1, k, cc0 + 1);
            const unsigned short* wnx = wbl + (cc0 + 1) * 10240;
#pragma unroll
            for (int kk = 0; kk < 9; ++kk)
                bfr[1][kk] = *(const bf16x8_t*)(wnx + kk * 102400);
            compute(&ylds[0][0], bfr[0]);
            __syncthreads();   // drains vmcnt -> A(cc0+1) in LDS, bfr[1] ready
        }
        // ---- odd cc: compute from buf1/bfr[1]; prefetch cc1+1 -> buf0/bfr[0]
        {
            if (cc1 < 9) {
#pragma unroll
                for (int k = 0; k < 5; ++k) GLDS(0, k, cc1 + 1);
                const unsigned short* wnx = wbl + (cc1 + 1) * 10240;
#pragma unroll
                for (int kk = 0; kk < 9; ++kk)
                    bfr[0][kk] = *(const bf16x8_t*)(wnx + kk * 102400);
            }
            compute(&ylds[1][0], bfr[1]);
            if (cc1 < 9) __syncthreads();
        }
    }
#undef GLDS

    // epilogue: D[row=co][col=m]; coalesced 64B segments
#pragma unroll
    for (int mf = 0; mf < 4; ++mf) {
        int oh = oh0 + mf;
        int ow = ow0 + lc;
#pragma unroll
        for (int rg = 0; rg < 4; ++rg) {
            int co = co0 + wid * 16 + q * 4 + rg;
            out[((n * CCH + co) * 32 + oh) * 32 + ow] = acc[mf][rg];
        }
    }
}

// ---------------- Fallback: naive direct (correct, slow) ----------------
__global__ __launch_bounds__(256) void naive_kernel(const float* __restrict__ x,
                                                    const float* __restrict__ w,
                                                    const float* __restrict__ fk,
                                                    float* __restrict__ out) {
    int idx = blockIdx.x * 256 + threadIdx.x;
    if (idx >= NI * CCH * 32 * 32) return;
    int ow = idx & 31;
    int oh = (idx >> 5) & 31;
    int co = (idx >> 10) % CCH;
    int n = (idx >> 10) / CCH;
    float f0 = fk[0] + fk[1] + fk[2] + fk[3];
    float f1 = fk[4] + fk[5] + fk[6] + fk[7];
    float f2 = fk[8] + fk[9] + fk[10] + fk[11];
    float f3 = fk[12] + fk[13] + fk[14] + fk[15];
    float fv[4] = {f0, f1, f2, f3};
    float acc = 0.f;
    for (int ci = 0; ci < CCH; ++ci) {
        const float* xb = x + (size_t)(n * CCH + ci) * HW * HW;
        const float* wb = w + (size_t)(co * CCH + ci) * 9;
#pragma unroll
        for (int u = 0; u < 3; ++u) {
            int yr = 2 * oh + u;
#pragma unroll
            for (int v = 0; v < 3; ++v) {
                int yc = 2 * ow + v;
                float s = 0.f;
#pragma unroll
                for (int a = 0; a < 4; ++a) {
                    int xrw = yr - 2 + a;
                    if (xrw < 0 || xrw >= HW) continue;
                    float t = 0.f;
#pragma unroll
                    for (int b = 0; b < 4; ++b) {
                        int xc = yc - 2 + b;
                        if (xc >= 0 && xc < HW) t += fv[b] * xb[xrw * HW + xc];
                    }
                    s += fv[a] * t;
                }
                acc += wb[u * 3 + v] * s;
            }
        }
    }
    out[idx] = acc;
}

extern "C" void kernel_launch(void* const* d_in, const int* in_sizes, int n_in,
                              void* d_out, int out_size, void* d_ws, size_t ws_size,
                              hipStream_t stream) {
    const float* x = (const float*)d_in[0];
    const float* w = (const float*)d_in[1];
    const float* fk = (const float*)d_in[2];
    float* out = (float*)d_out;

    const size_t ybytes = (size_t)NI * 40 * HY2 * 8 * 2;      // 43,264,000
    const size_t wtoff = ybytes;
    const size_t need = wtoff + (size_t)9 * CCH * CCH * 2;    // 45,107,200

    if (ws_size >= need) {
        __hip_bfloat16* yt = (__hip_bfloat16*)d_ws;
        __hip_bfloat16* wt = (__hip_bfloat16*)((char*)d_ws + wtoff);
        fir_kernel<<<16 * 9 * 20, 256, 0, stream>>>(x, fk, yt);
        wt2_kernel<<<(9 * CCH * CCH + 255) / 256, 256, 0, stream>>>(w, wt);
        conv_kernel<<<16 * 5 * 16, 256, 0, stream>>>(yt, wt, out);
    } else {
        naive_kernel<<<(NI * CCH * 32 * 32 + 255) / 256, 256, 0, stream>>>(x, w, fk, out);
    }
}

// Round 10
// 77.639 us; speedup vs baseline: 1.0209x; 1.0176x over previous
//
#include <hip/hip_runtime.h>
#include <hip/hip_bf16.h>

// FirDownsample: y = depthwise FIR(4x4 separable [1,3,3,1]) on x (pad 2),
// out = conv3x3(y, w), stride 2.  x:(16,320,64,64) f32, out:(16,320,32,32) f32.
//
// R10: y reverted to packed-32 [n][cc][r][c][32] and conv reverted to the exact
// R6 configuration (measured ~23us). fir keeps R7's transposed-vlds structure but
// stores 16B octet pairs into the packed-32 layout (32B-dense wave stores).
//   K1 fir_kernel : x -> y[n][cc=10][65][65][32ci] bf16
//   K2 wt2_kernel : w -> wt2[tap][cc][q][co][8ci] bf16
//   K3 conv_kernel: M64xN64 block, 4 waves M64xN16, B reg-dbuf, A via global_load_lds.

typedef short bf16x8_t __attribute__((ext_vector_type(8)));
typedef float f32x4 __attribute__((ext_vector_type(4)));
typedef unsigned int u32x4 __attribute__((ext_vector_type(4)));
typedef __attribute__((address_space(1))) const unsigned int* as1_u32p;
typedef __attribute__((address_space(3))) unsigned int* as3_u32p;

#define NI 16
#define CCH 320
#define HW 64
#define HY 65
#define HY2 4225           // 65*65
#define CCSTEP 135200      // 4225*32 shorts per cc-plane

// ---------------- K1: separable FIR, x(f32) -> y bf16 [n][cc][r][c][32] ----------------
// block = (n, row-band of 8, 16-ci group). vert pass -> LDS [j][ci16][69] f32,
// horiz pass: thread owns (c, ci-octet of 2) -> paired 16B stores (32B dense).
__global__ __launch_bounds__(256) void fir_kernel(const float* __restrict__ x,
                                                  const float* __restrict__ fir_k,
                                                  __hip_bfloat16* __restrict__ yt) {
    __shared__ float vlds[8 * 16 * 69];  // [j][ci16][cc69] : 35,328 B
    int bx = blockIdx.x;
    int n   = bx / 180;
    int rr  = bx % 180;
    int r0  = (rr / 20) * 8;
    int cig = rr % 20;           // 16-ci group
    int ci0 = cig * 16;

    float f0 = fir_k[0] + fir_k[1] + fir_k[2] + fir_k[3];
    float f1 = fir_k[4] + fir_k[5] + fir_k[6] + fir_k[7];
    float f2 = fir_k[8] + fir_k[9] + fir_k[10] + fir_k[11];
    float f3 = fir_k[12] + fir_k[13] + fir_k[14] + fir_k[15];

    int tid = threadIdx.x;
    int lane = tid & 63;   // = w (vert)
    int g = tid >> 6;      // wave id

    // vertical pass: vert[j][ci][w+2] = sum_a f[a] * x[r0+j-2+a][w]
    for (int cis = g; cis < 16; cis += 4) {
        int ci = ci0 + cis;
        const float* xb = x + (size_t)(n * CCH + ci) * HW * HW;
        float xr[11];
#pragma unroll
        for (int jr = 0; jr < 11; ++jr) {
            int row = r0 + jr - 2;
            xr[jr] = (row >= 0 && row < HW) ? xb[row * HW + lane] : 0.f;
        }
#pragma unroll
        for (int j = 0; j < 8; ++j) {
            float v = f0 * xr[j] + f1 * xr[j + 1] + f2 * xr[j + 2] + f3 * xr[j + 3];
            float* vrow = vlds + (j * 16 + cis) * 69;
            vrow[lane + 2] = v;                       // cc = w+2 (2..65)
            if (lane < 2)   vrow[lane] = 0.f;         // cc 0,1
            if (lane >= 62) vrow[lane + 4] = 0.f;     // cc 66,67
        }
    }
    __syncthreads();

    // horizontal pass into packed-32 y: [n][cc][r][c][32], this block owns octets O,O+1
    int cc = cig >> 1;
    int O  = (cig & 1) * 2;
    unsigned short* yu = (unsigned short*)yt;
    int oct = lane & 1;          // octet within pair
    int cl  = lane >> 1;         // 0..31
    size_t pbase = (size_t)(n * 10 + cc) * HY2;
#pragma unroll
    for (int i = 0; i < 4; ++i) {
        int slot = 4 * i + g;            // 0..15
        int j = slot >> 1, half = slot & 1;
        int r = r0 + j;
        if (r >= HY) continue;
        int c = half * 32 + cl;          // 0..63
        const float* vb = vlds + (j * 16 + oct * 8) * 69 + c;
        float a[8];
#pragma unroll
        for (int u = 0; u < 8; ++u) {
            const float* vr = vb + u * 69;
            a[u] = f0 * vr[0] + f1 * vr[1] + f2 * vr[2] + f3 * vr[3];
        }
        unsigned int wd[4];
#pragma unroll
        for (int h = 0; h < 4; ++h) {
            unsigned int lo = __bfloat16_as_ushort(__float2bfloat16(a[2 * h]));
            unsigned int hi = __bfloat16_as_ushort(__float2bfloat16(a[2 * h + 1]));
            wd[h] = lo | (hi << 16);
        }
        *(u32x4*)(yu + (pbase + (size_t)r * HY + c) * 32 + (O + oct) * 8) =
            (u32x4){wd[0], wd[1], wd[2], wd[3]};
    }
    // tail: c == 64
    if (tid < 16) {
        int j = tid >> 1, oc2 = tid & 1;
        int r = r0 + j;
        if (r < HY) {
            const float* vb = vlds + (j * 16 + oc2 * 8) * 69 + 64;
            float a[8];
#pragma unroll
            for (int u = 0; u < 8; ++u) {
                const float* vr = vb + u * 69;
                a[u] = f0 * vr[0] + f1 * vr[1] + f2 * vr[2] + f3 * vr[3];
            }
            unsigned int wd[4];
#pragma unroll
            for (int h = 0; h < 4; ++h) {
                unsigned int lo = __bfloat16_as_ushort(__float2bfloat16(a[2 * h]));
                unsigned int hi = __bfloat16_as_ushort(__float2bfloat16(a[2 * h + 1]));
                wd[h] = lo | (hi << 16);
            }
            *(u32x4*)(yu + (pbase + (size_t)r * HY + 64) * 32 + (O + oc2) * 8) =
                (u32x4){wd[0], wd[1], wd[2], wd[3]};
        }
    }
}

// ---------------- K2: w (co,ci,3,3) f32 -> wt2[tap][cc][q][co][8] bf16 ----------------
__global__ __launch_bounds__(256) void wt2_kernel(const float* __restrict__ w,
                                                  __hip_bfloat16* __restrict__ wt) {
    int idx = blockIdx.x * 256 + threadIdx.x;
    if (idx < 9 * CCH * CCH) {
        int j  = idx & 7;
        int co = (idx >> 3) % CCH;
        int t2 = idx / 2560;          // tap*40 + cc*4 + q
        int q  = t2 & 3;
        int cc = (t2 >> 2) % 10;
        int tap = t2 / 40;
        int ci = cc * 32 + q * 8 + j;
        wt[idx] = __float2bfloat16(w[(co * CCH + ci) * 9 + tap]);
    }
}

// ---------------- K3: MFMA conv, M64 x N64, waves M64xN16, B reg-dbuf (exact R6) ----------------
// grid = (n*5 + cb)*16 + sp ; wave wid owns co chunk wid*16.
// LDS: dbuf of 1536 16B-units; pos p = units 5p..5p+3 (+1 pad) -> 80B row pitch,
// conflict-free b128 reads. A staged via global_load_lds width 16.
__global__ __launch_bounds__(256, 3) void conv_kernel(const __hip_bfloat16* __restrict__ yt,
                                                      const __hip_bfloat16* __restrict__ wt2,
                                                      float* __restrict__ out) {
    __shared__ short ylds[2][1536 * 8];   // 2 x 24,576 B

    int bx = blockIdx.x;
    int sp = bx & 15;
    int t  = bx >> 4;
    int cb = t % 5;
    int n  = t / 5;
    int co0 = cb * 64;
    int oh0 = (sp >> 1) * 4;
    int ow0 = (sp & 1) * 16;

    int tid = threadIdx.x;
    int lane = tid & 63;
    int wid = tid >> 6;
    int q = lane >> 4, lc = lane & 15;

    const unsigned short* ytu = (const unsigned short*)yt;
    const unsigned short* wtu = (const unsigned short*)wt2;

    // per-lane global source offsets (shorts) for staging units, cc=0
    int ybase = (n * 10 * HY2 + (2 * oh0) * HY + 2 * ow0) * 32;
    int goff[6];
#pragma unroll
    for (int k = 0; k < 6; ++k) {
        int u = k * 256 + tid;
        int uc = (u < 1485) ? u : 1484;    // tail: safe dup, lands in pad units
        int p = uc / 5, s = uc - p * 5;
        if (s == 4) s = 3;                 // row-pad unit: dup of unit 3, never read
        int pr = p / 33, pc = p - pr * 33;
        goff[k] = ybase + (pr * HY + pc) * 32 + s * 8;
    }

    const unsigned short* wbl = wtu + q * 2560 + (size_t)(co0 + wid * 16 + lc) * 8;
    const int aoff = (2 * lc) * 40 + q * 8;   // short-index within buffer

    f32x4 acc[4];
#pragma unroll
    for (int i = 0; i < 4; ++i) acc[i] = (f32x4){0.f, 0.f, 0.f, 0.f};

    bf16x8_t bfr[2][9];

    // wave-uniform LDS unit base for stage issue k: (k*256 + wid*64) units
#define GLDS(buf, K, ccidx)                                                            \
    __builtin_amdgcn_global_load_lds(                                                  \
        (as1_u32p)(ytu + goff[K] + (ccidx) * CCSTEP),                                  \
        (as3_u32p)(&ylds[buf][(size_t)((K) * 256 + wid * 64) * 8]), 16, 0, 0)

    // prologue: stage A(0) -> buf0, load B(0) -> bfr[0]
#pragma unroll
    for (int k = 0; k < 6; ++k) GLDS(0, k, 0);
#pragma unroll
    for (int kk = 0; kk < 9; ++kk)
        bfr[0][kk] = *(const bf16x8_t*)(wbl + kk * 102400);
    __syncthreads();

    auto compute = [&](const short* buf, const bf16x8_t* b) {
#pragma unroll
        for (int kw = 0; kw < 3; ++kw) {
            bf16x8_t af[9];
#pragma unroll
            for (int r = 0; r < 9; ++r)
                af[r] = *(const bf16x8_t*)(buf + aoff + (r * 33 + kw) * 40);
#pragma unroll
            for (int kh = 0; kh < 3; ++kh)
#pragma unroll
                for (int mf = 0; mf < 4; ++mf)
                    acc[mf] = __builtin_amdgcn_mfma_f32_16x16x32_bf16(
                        b[kh * 3 + kw], af[2 * mf + kh], acc[mf], 0, 0, 0);
        }
    };

    for (int tt = 0; tt < 5; ++tt) {
        int cc0 = 2 * tt, cc1 = 2 * tt + 1;
        // ---- even cc: compute from buf0/bfr[0]; prefetch cc0+1 -> buf1/bfr[1]
        {
#pragma unroll
            for (int k = 0; k < 6; ++k) GLDS(1, k, cc0 + 1);
            const unsigned short* wnx = wbl + (cc0 + 1) * 10240;
#pragma unroll
            for (int kk = 0; kk < 9; ++kk)
                bfr[1][kk] = *(const bf16x8_t*)(wnx + kk * 102400);
            compute(&ylds[0][0], bfr[0]);
            __syncthreads();   // drains vmcnt -> A(cc0+1) in LDS, bfr[1] ready
        }
        // ---- odd cc: compute from buf1/bfr[1]; prefetch cc1+1 -> buf0/bfr[0]
        {
            if (cc1 < 9) {
#pragma unroll
                for (int k = 0; k < 6; ++k) GLDS(0, k, cc1 + 1);
                const unsigned short* wnx = wbl + (cc1 + 1) * 10240;
#pragma unroll
                for (int kk = 0; kk < 9; ++kk)
                    bfr[0][kk] = *(const bf16x8_t*)(wnx + kk * 102400);
            }
            compute(&ylds[1][0], bfr[1]);
            if (cc1 < 9) __syncthreads();
        }
    }
#undef GLDS

    // epilogue: D[row=co][col=m]; coalesced 64B segments
#pragma unroll
    for (int mf = 0; mf < 4; ++mf) {
        int oh = oh0 + mf;
        int ow = ow0 + lc;
#pragma unroll
        for (int rg = 0; rg < 4; ++rg) {
            int co = co0 + wid * 16 + q * 4 + rg;
            out[((n * CCH + co) * 32 + oh) * 32 + ow] = acc[mf][rg];
        }
    }
}

// ---------------- Fallback: naive direct (correct, slow) ----------------
__global__ __launch_bounds__(256) void naive_kernel(const float* __restrict__ x,
                                                    const float* __restrict__ w,
                                                    const float* __restrict__ fk,
                                                    float* __restrict__ out) {
    int idx = blockIdx.x * 256 + threadIdx.x;
    if (idx >= NI * CCH * 32 * 32) return;
    int ow = idx & 31;
    int oh = (idx >> 5) & 31;
    int co = (idx >> 10) % CCH;
    int n = (idx >> 10) / CCH;
    float f0 = fk[0] + fk[1] + fk[2] + fk[3];
    float f1 = fk[4] + fk[5] + fk[6] + fk[7];
    float f2 = fk[8] + fk[9] + fk[10] + fk[11];
    float f3 = fk[12] + fk[13] + fk[14] + fk[15];
    float fv[4] = {f0, f1, f2, f3};
    float acc = 0.f;
    for (int ci = 0; ci < CCH; ++ci) {
        const float* xb = x + (size_t)(n * CCH + ci) * HW * HW;
        const float* wb = w + (size_t)(co * CCH + ci) * 9;
#pragma unroll
        for (int u = 0; u < 3; ++u) {
            int yr = 2 * oh + u;
#pragma unroll
            for (int v = 0; v < 3; ++v) {
                int yc = 2 * ow + v;
                float s = 0.f;
#pragma unroll
                for (int a = 0; a < 4; ++a) {
                    int xrw = yr - 2 + a;
                    if (xrw < 0 || xrw >= HW) continue;
                    float t = 0.f;
#pragma unroll
                    for (int b = 0; b < 4; ++b) {
                        int xc = yc - 2 + b;
                        if (xc >= 0 && xc < HW) t += fv[b] * xb[xrw * HW + xc];
                    }
                    s += fv[a] * t;
                }
                acc += wb[u * 3 + v] * s;
            }
        }
    }
    out[idx] = acc;
}

extern "C" void kernel_launch(void* const* d_in, const int* in_sizes, int n_in,
                              void* d_out, int out_size, void* d_ws, size_t ws_size,
                              hipStream_t stream) {
    const float* x = (const float*)d_in[0];
    const float* w = (const float*)d_in[1];
    const float* fk = (const float*)d_in[2];
    float* out = (float*)d_out;

    const size_t ybytes = (size_t)NI * 10 * HY2 * 32 * 2;     // 43,264,000
    const size_t wtoff = ybytes;
    const size_t need = wtoff + (size_t)9 * CCH * CCH * 2;    // 45,107,200

    if (ws_size >= need) {
        __hip_bfloat16* yt = (__hip_bfloat16*)d_ws;
        __hip_bfloat16* wt = (__hip_bfloat16*)((char*)d_ws + wtoff);
        fir_kernel<<<16 * 9 * 20, 256, 0, stream>>>(x, fk, yt);
        wt2_kernel<<<(9 * CCH * CCH + 255) / 256, 256, 0, stream>>>(w, wt);
        conv_kernel<<<16 * 5 * 16, 256, 0, stream>>>(yt, wt, out);
    } else {
        naive_kernel<<<(NI * CCH * 32 * 32 + 255) / 256, 256, 0, stream>>>(x, w, fk, out);
    }
}

// Round 11
// 76.419 us; speedup vs baseline: 1.0372x; 1.0160x over previous
//
#include <hip/hip_runtime.h>
#include <hip/hip_bf16.h>

// FirDownsample: y = depthwise FIR(4x4 separable [1,3,3,1]) on x (pad 2),
// out = conv3x3(y, w), stride 2.  x:(16,320,64,64) f32, out:(16,320,32,32) f32.
//
// R11: fir re-tiled ci-complete: block = (n, 4-row band, cc-plane of 32 ci),
// vlds [4][32][69] f32; horiz thread = (position, octet) -> 4 lanes fill one
// position's 64B -> fully dense 1KB wave-stores into packed-32 y.
// conv and wt2 byte-identical to R10 (conv measured ~23us).
//   K1 fir_kernel : x -> y[n][cc=10][65][65][32ci] bf16
//   K2 wt2_kernel : w -> wt2[tap][cc][q][co][8ci] bf16
//   K3 conv_kernel: M64xN64 block, 4 waves M64xN16, B reg-dbuf, A via global_load_lds.

typedef short bf16x8_t __attribute__((ext_vector_type(8)));
typedef float f32x4 __attribute__((ext_vector_type(4)));
typedef unsigned int u32x4 __attribute__((ext_vector_type(4)));
typedef __attribute__((address_space(1))) const unsigned int* as1_u32p;
typedef __attribute__((address_space(3))) unsigned int* as3_u32p;

#define NI 16
#define CCH 320
#define HW 64
#define HY 65
#define HY2 4225           // 65*65
#define CCSTEP 135200      // 4225*32 shorts per cc-plane

// ---------------- K1: separable FIR, x(f32) -> y bf16 [n][cc][r][c][32] ----------------
// block = (n, 4-row band, cc). vert: vlds[j][ci32][cc69] f32. horiz: thread =
// (pos, octet s): reads 8 ci x 4 taps from vlds, stores 16B; 4 lanes/pos -> dense.
__global__ __launch_bounds__(256) void fir_kernel(const float* __restrict__ x,
                                                  const float* __restrict__ fir_k,
                                                  __hip_bfloat16* __restrict__ yt) {
    __shared__ float vlds[4 * 32 * 69];  // [j4][ci32][69] : 35,328 B
    int bx = blockIdx.x;
    int n    = bx / 170;
    int rem  = bx % 170;
    int band = rem / 10;
    int cc   = rem % 10;
    int r0   = band * 4;

    float f0 = fir_k[0] + fir_k[1] + fir_k[2] + fir_k[3];
    float f1 = fir_k[4] + fir_k[5] + fir_k[6] + fir_k[7];
    float f2 = fir_k[8] + fir_k[9] + fir_k[10] + fir_k[11];
    float f3 = fir_k[12] + fir_k[13] + fir_k[14] + fir_k[15];

    int tid = threadIdx.x;
    int lane = tid & 63;   // = w (vert)
    int g = tid >> 6;      // wave id

    // vertical pass: vlds[j][cis][w+2] = sum_a f[a] * x[r0+j-2+a][w]
    for (int cis = g; cis < 32; cis += 4) {
        int ci = cc * 32 + cis;
        const float* xb = x + (size_t)(n * CCH + ci) * HW * HW;
        float xr[7];
#pragma unroll
        for (int t = 0; t < 7; ++t) {
            int row = r0 + t - 2;
            xr[t] = (row >= 0 && row < HW) ? xb[row * HW + lane] : 0.f;
        }
#pragma unroll
        for (int j = 0; j < 4; ++j) {
            float v = f0 * xr[j] + f1 * xr[j + 1] + f2 * xr[j + 2] + f3 * xr[j + 3];
            float* vrow = vlds + (j * 32 + cis) * 69;
            vrow[lane + 2] = v;                       // cc = w+2 (2..65)
            if (lane < 2)   vrow[lane] = 0.f;         // cc 0,1
            if (lane >= 62) vrow[lane + 4] = 0.f;     // cc 66,67
        }
    }
    __syncthreads();

    // horizontal pass: thread = (pos_id, s); pos_id = (j, c); 4 lanes fill 64B/pos
    unsigned short* yu = (unsigned short*)yt;
    int s  = tid & 3;
    int pl = tid >> 2;               // 0..63
    size_t plane = (size_t)(n * 10 + cc) * HY2;
#pragma unroll
    for (int it = 0; it < 5; ++it) {
        int pid = it * 64 + pl;      // 0..319; valid < 260
        if (pid < 260) {
            int j = pid / 65;
            int c = pid % 65;
            int r = r0 + j;
            if (r < HY) {
                const float* vb = vlds + (j * 32 + s * 8) * 69 + c;
                float a[8];
#pragma unroll
                for (int k = 0; k < 8; ++k) {
                    const float* vr = vb + k * 69;
                    a[k] = f0 * vr[0] + f1 * vr[1] + f2 * vr[2] + f3 * vr[3];
                }
                unsigned int wd[4];
#pragma unroll
                for (int h = 0; h < 4; ++h) {
                    unsigned int lo = __bfloat16_as_ushort(__float2bfloat16(a[2 * h]));
                    unsigned int hi = __bfloat16_as_ushort(__float2bfloat16(a[2 * h + 1]));
                    wd[h] = lo | (hi << 16);
                }
                *(u32x4*)(yu + (plane + (size_t)r * HY + c) * 32 + s * 8) =
                    (u32x4){wd[0], wd[1], wd[2], wd[3]};
            }
        }
    }
}

// ---------------- K2: w (co,ci,3,3) f32 -> wt2[tap][cc][q][co][8] bf16 ----------------
__global__ __launch_bounds__(256) void wt2_kernel(const float* __restrict__ w,
                                                  __hip_bfloat16* __restrict__ wt) {
    int idx = blockIdx.x * 256 + threadIdx.x;
    if (idx < 9 * CCH * CCH) {
        int j  = idx & 7;
        int co = (idx >> 3) % CCH;
        int t2 = idx / 2560;          // tap*40 + cc*4 + q
        int q  = t2 & 3;
        int cc = (t2 >> 2) % 10;
        int tap = t2 / 40;
        int ci = cc * 32 + q * 8 + j;
        wt[idx] = __float2bfloat16(w[(co * CCH + ci) * 9 + tap]);
    }
}

// ---------------- K3: MFMA conv, M64 x N64, waves M64xN16, B reg-dbuf (exact R6) ----------------
// grid = (n*5 + cb)*16 + sp ; wave wid owns co chunk wid*16.
// LDS: dbuf of 1536 16B-units; pos p = units 5p..5p+3 (+1 pad) -> 80B row pitch,
// conflict-free b128 reads. A staged via global_load_lds width 16.
__global__ __launch_bounds__(256, 3) void conv_kernel(const __hip_bfloat16* __restrict__ yt,
                                                      const __hip_bfloat16* __restrict__ wt2,
                                                      float* __restrict__ out) {
    __shared__ short ylds[2][1536 * 8];   // 2 x 24,576 B

    int bx = blockIdx.x;
    int sp = bx & 15;
    int t  = bx >> 4;
    int cb = t % 5;
    int n  = t / 5;
    int co0 = cb * 64;
    int oh0 = (sp >> 1) * 4;
    int ow0 = (sp & 1) * 16;

    int tid = threadIdx.x;
    int lane = tid & 63;
    int wid = tid >> 6;
    int q = lane >> 4, lc = lane & 15;

    const unsigned short* ytu = (const unsigned short*)yt;
    const unsigned short* wtu = (const unsigned short*)wt2;

    // per-lane global source offsets (shorts) for staging units, cc=0
    int ybase = (n * 10 * HY2 + (2 * oh0) * HY + 2 * ow0) * 32;
    int goff[6];
#pragma unroll
    for (int k = 0; k < 6; ++k) {
        int u = k * 256 + tid;
        int uc = (u < 1485) ? u : 1484;    // tail: safe dup, lands in pad units
        int p = uc / 5, s = uc - p * 5;
        if (s == 4) s = 3;                 // row-pad unit: dup of unit 3, never read
        int pr = p / 33, pc = p - pr * 33;
        goff[k] = ybase + (pr * HY + pc) * 32 + s * 8;
    }

    const unsigned short* wbl = wtu + q * 2560 + (size_t)(co0 + wid * 16 + lc) * 8;
    const int aoff = (2 * lc) * 40 + q * 8;   // short-index within buffer

    f32x4 acc[4];
#pragma unroll
    for (int i = 0; i < 4; ++i) acc[i] = (f32x4){0.f, 0.f, 0.f, 0.f};

    bf16x8_t bfr[2][9];

    // wave-uniform LDS unit base for stage issue k: (k*256 + wid*64) units
#define GLDS(buf, K, ccidx)                                                            \
    __builtin_amdgcn_global_load_lds(                                                  \
        (as1_u32p)(ytu + goff[K] + (ccidx) * CCSTEP),                                  \
        (as3_u32p)(&ylds[buf][(size_t)((K) * 256 + wid * 64) * 8]), 16, 0, 0)

    // prologue: stage A(0) -> buf0, load B(0) -> bfr[0]
#pragma unroll
    for (int k = 0; k < 6; ++k) GLDS(0, k, 0);
#pragma unroll
    for (int kk = 0; kk < 9; ++kk)
        bfr[0][kk] = *(const bf16x8_t*)(wbl + kk * 102400);
    __syncthreads();

    auto compute = [&](const short* buf, const bf16x8_t* b) {
#pragma unroll
        for (int kw = 0; kw < 3; ++kw) {
            bf16x8_t af[9];
#pragma unroll
            for (int r = 0; r < 9; ++r)
                af[r] = *(const bf16x8_t*)(buf + aoff + (r * 33 + kw) * 40);
#pragma unroll
            for (int kh = 0; kh < 3; ++kh)
#pragma unroll
                for (int mf = 0; mf < 4; ++mf)
                    acc[mf] = __builtin_amdgcn_mfma_f32_16x16x32_bf16(
                        b[kh * 3 + kw], af[2 * mf + kh], acc[mf], 0, 0, 0);
        }
    };

    for (int tt = 0; tt < 5; ++tt) {
        int cc0 = 2 * tt, cc1 = 2 * tt + 1;
        // ---- even cc: compute from buf0/bfr[0]; prefetch cc0+1 -> buf1/bfr[1]
        {
#pragma unroll
            for (int k = 0; k < 6; ++k) GLDS(1, k, cc0 + 1);
            const unsigned short* wnx = wbl + (cc0 + 1) * 10240;
#pragma unroll
            for (int kk = 0; kk < 9; ++kk)
                bfr[1][kk] = *(const bf16x8_t*)(wnx + kk * 102400);
            compute(&ylds[0][0], bfr[0]);
            __syncthreads();   // drains vmcnt -> A(cc0+1) in LDS, bfr[1] ready
        }
        // ---- odd cc: compute from buf1/bfr[1]; prefetch cc1+1 -> buf0/bfr[0]
        {
            if (cc1 < 9) {
#pragma unroll
                for (int k = 0; k < 6; ++k) GLDS(0, k, cc1 + 1);
                const unsigned short* wnx = wbl + (cc1 + 1) * 10240;
#pragma unroll
                for (int kk = 0; kk < 9; ++kk)
                    bfr[0][kk] = *(const bf16x8_t*)(wnx + kk * 102400);
            }
            compute(&ylds[1][0], bfr[1]);
            if (cc1 < 9) __syncthreads();
        }
    }
#undef GLDS

    // epilogue: D[row=co][col=m]; coalesced 64B segments
#pragma unroll
    for (int mf = 0; mf < 4; ++mf) {
        int oh = oh0 + mf;
        int ow = ow0 + lc;
#pragma unroll
        for (int rg = 0; rg < 4; ++rg) {
            int co = co0 + wid * 16 + q * 4 + rg;
            out[((n * CCH + co) * 32 + oh) * 32 + ow] = acc[mf][rg];
        }
    }
}

// ---------------- Fallback: naive direct (correct, slow) ----------------
__global__ __launch_bounds__(256) void naive_kernel(const float* __restrict__ x,
                                                    const float* __restrict__ w,
                                                    const float* __restrict__ fk,
                                                    float* __restrict__ out) {
    int idx = blockIdx.x * 256 + threadIdx.x;
    if (idx >= NI * CCH * 32 * 32) return;
    int ow = idx & 31;
    int oh = (idx >> 5) & 31;
    int co = (idx >> 10) % CCH;
    int n = (idx >> 10) / CCH;
    float f0 = fk[0] + fk[1] + fk[2] + fk[3];
    float f1 = fk[4] + fk[5] + fk[6] + fk[7];
    float f2 = fk[8] + fk[9] + fk[10] + fk[11];
    float f3 = fk[12] + fk[13] + fk[14] + fk[15];
    float fv[4] = {f0, f1, f2, f3};
    float acc = 0.f;
    for (int ci = 0; ci < CCH; ++ci) {
        const float* xb = x + (size_t)(n * CCH + ci) * HW * HW;
        const float* wb = w + (size_t)(co * CCH + ci) * 9;
#pragma unroll
        for (int u = 0; u < 3; ++u) {
            int yr = 2 * oh + u;
#pragma unroll
            for (int v = 0; v < 3; ++v) {
                int yc = 2 * ow + v;
                float s = 0.f;
#pragma unroll
                for (int a = 0; a < 4; ++a) {
                    int xrw = yr - 2 + a;
                    if (xrw < 0 || xrw >= HW) continue;
                    float t = 0.f;
#pragma unroll
                    for (int b = 0; b < 4; ++b) {
                        int xc = yc - 2 + b;
                        if (xc >= 0 && xc < HW) t += fv[b] * xb[xrw * HW + xc];
                    }
                    s += fv[a] * t;
                }
                acc += wb[u * 3 + v] * s;
            }
        }
    }
    out[idx] = acc;
}

extern "C" void kernel_launch(void* const* d_in, const int* in_sizes, int n_in,
                              void* d_out, int out_size, void* d_ws, size_t ws_size,
                              hipStream_t stream) {
    const float* x = (const float*)d_in[0];
    const float* w = (const float*)d_in[1];
    const float* fk = (const float*)d_in[2];
    float* out = (float*)d_out;

    const size_t ybytes = (size_t)NI * 10 * HY2 * 32 * 2;     // 43,264,000
    const size_t wtoff = ybytes;
    const size_t need = wtoff + (size_t)9 * CCH * CCH * 2;    // 45,107,200

    if (ws_size >= need) {
        __hip_bfloat16* yt = (__hip_bfloat16*)d_ws;
        __hip_bfloat16* wt = (__hip_bfloat16*)((char*)d_ws + wtoff);
        fir_kernel<<<16 * 17 * 10, 256, 0, stream>>>(x, fk, yt);
        wt2_kernel<<<(9 * CCH * CCH + 255) / 256, 256, 0, stream>>>(w, wt);
        conv_kernel<<<16 * 5 * 16, 256, 0, stream>>>(yt, wt, out);
    } else {
        naive_kernel<<<(NI * CCH * 32 * 32 + 255) / 256, 256, 0, stream>>>(x, w, fk, out);
    }
}